// Round 1
// baseline (192.998 us; speedup 1.0000x reference)
//
#include <hip/hip_runtime.h>
#include <math.h>

#define NWG 256
#define NPAIR 128
#define NITER 3
#define NBATCH 8192
#define KDIM 512
#define MSZ (512*512)   // elems per embedded matrix

typedef __attribute__((ext_vector_type(8))) short short8;
typedef __attribute__((ext_vector_type(4))) float floatx4;

static __device__ __forceinline__ unsigned short f2bf(float f) {
    unsigned int u = __float_as_uint(f);
    unsigned int r = (u + 0x7fffu + ((u >> 16) & 1u)) >> 16;
    return (unsigned short)r;
}
static __device__ __forceinline__ float bf2f(unsigned short h) {
    return __uint_as_float(((unsigned int)h) << 16);
}
static __device__ __forceinline__ void bsplit(float v, unsigned short &h, unsigned short &l) {
    h = f2bf(v);
    l = f2bf(v - bf2f(h));
}
static __device__ __forceinline__ void async16(const void* g, void* l) {
    __builtin_amdgcn_global_load_lds(
        (const __attribute__((address_space(1))) unsigned int*)g,
        (__attribute__((address_space(3))) unsigned int*)l, 16, 0, 0);
}

static __device__ __forceinline__ void apply2(
    float &x0r, float &x0i, float &x1r, float &x1i,
    const float4 a, const float4 b)
{
    float y0r = a.x*x0r - a.y*x0i + a.z*x1r - a.w*x1i;
    float y0i = a.x*x0i + a.y*x0r + a.z*x1i + a.w*x1r;
    float y1r = b.x*x0r - b.y*x0i + b.z*x1r - b.w*x1i;
    float y1i = b.x*x0i + b.y*x0r + b.z*x1i + b.w*x1r;
    x0r = y0r; x0i = y0i; x1r = y1r; x1i = y1i;
}

// coef: rows (A,B),(C,D); coefT: transposed rows (A,C),(B,D); gexp: {cos,sin}
__global__ void precompute_kernel(const float* __restrict__ theta,
                                  const float* __restrict__ phi,
                                  const float* __restrict__ gamma,
                                  float* __restrict__ coef,
                                  float* __restrict__ coefT,
                                  float* __restrict__ gexp)
{
    int idx = blockIdx.x * blockDim.x + threadIdx.x;
    if (idx < NITER * NWG * NPAIR) {
        float h  = 0.5f * theta[idx];
        float ph = phi[idx];
        float sh = sinf(h),  ch = cosf(h);
        float sp = sinf(ph), cp = cosf(ph);
        float pr = -sh, pii = ch;            // pre = i*exp(i*h)
        float qr = pr*cp - pii*sp;           // pre*exp(i*ph)
        float qi = pr*sp + pii*cp;
        float Ar = qr*sh,  Ai = qi*sh;
        float Br = pr*ch,  Bi = pii*ch;
        float Cr = qr*ch,  Ci = qi*ch;
        float Dr = -pr*sh, Di = -pii*sh;
        float4* o = (float4*)coef + (size_t)idx * 2;
        o[0] = make_float4(Ar,Ai,Br,Bi);
        o[1] = make_float4(Cr,Ci,Dr,Di);
        float4* ot = (float4*)coefT + (size_t)idx * 2;
        ot[0] = make_float4(Ar,Ai,Cr,Ci);
        ot[1] = make_float4(Br,Bi,Dr,Di);
    }
    if (idx < NITER * NWG) {
        float g = gamma[idx];
        gexp[idx*2]   = cosf(g);
        gexp[idx*2+1] = sinf(g);
    }
}

// ---------- propagate: coefficient bundles + unrolled layer loop ----------
// Even layer: pairs (4l,4l+1)->c0, (4l+2,4l+3)->c1, all in-lane.
// Odd layer:  interior (4l+1,4l+2)->c0; boundary (4l+3, next-lane x0)->c1;
//             THIS lane's new x0 comes from pair 2l-1 row b ("m1", at p[-1]).
struct CoefE { float4 a0, b0, a1, b1; };
struct CoefO { float4 a0, b0, a1, b1, m1; };

static __device__ __forceinline__ void loadE(const float4* cb, int row, int lane, CoefE &c) {
    const float4* p = cb + (ptrdiff_t)row * (NPAIR*2) + 4*lane;
    c.a0 = p[0]; c.b0 = p[1]; c.a1 = p[2]; c.b1 = p[3];
}
static __device__ __forceinline__ void loadO(const float4* cb, int row, int lane, CoefO &c) {
    const float4* p = cb + (ptrdiff_t)row * (NPAIR*2) + 4*lane;
    c.m1 = p[-1]; c.a0 = p[0]; c.b0 = p[1]; c.a1 = p[2]; c.b1 = p[3];
}

static __device__ __forceinline__ void applyE(const CoefE &c, float xr[4], float xi[4]) {
    apply2(xr[0], xi[0], xr[1], xi[1], c.a0, c.b0);
    apply2(xr[2], xi[2], xr[3], xi[3], c.a1, c.b1);
}

static __device__ __forceinline__ void applyO(const CoefO &c, float xr[4], float xi[4], int lane) {
    // all four cross-lane reads are independent -> one LDS-pipe round-trip
    float tr = __shfl_down(xr[0], 1, 64);   // x0 of lane+1 (boundary partner above)
    float ti = __shfl_down(xi[0], 1, 64);
    float br = __shfl_up(xr[3], 1, 64);     // x3 of lane-1 (boundary partner below)
    float bi = __shfl_up(xi[3], 1, 64);
    apply2(xr[1], xi[1], xr[2], xi[2], c.a0, c.b0);
    float y3r = c.a1.x*xr[3] - c.a1.y*xi[3] + c.a1.z*tr - c.a1.w*ti;
    float y3i = c.a1.x*xi[3] + c.a1.y*xr[3] + c.a1.z*ti + c.a1.w*tr;
    float n0r = c.m1.x*br - c.m1.y*bi + c.m1.z*xr[0] - c.m1.w*xi[0];
    float n0i = c.m1.x*bi + c.m1.y*br + c.m1.z*xi[0] + c.m1.w*xr[0];
    if (lane != 63) { xr[3] = y3r; xi[3] = y3i; }   // wrap pair inactive
    if (lane != 0)  { xr[0] = n0r; xi[0] = n0i; }
}

// forward: layers 0(E),1(O),2(E),...,63(O); prefetch 2 layers ahead (ping-pong).
static __device__ __forceinline__ void prop_fwd(const float4* cb, int lane,
                                                float xr[4], float xi[4]) {
    CoefE e0, e1; CoefO o0, o1;
    loadE(cb, 0, lane, e0);
    loadO(cb, 1, lane, o0);
    for (int i = 0; i < 16; ++i) {
        loadE(cb, 4*i+2, lane, e1);       // i=15 -> rows 64/65: in-bounds over-read,
        loadO(cb, 4*i+3, lane, o1);       // values never used (fwd base <= row 640 of 768)
        applyE(e0, xr, xi);
        applyO(o0, xr, xi, lane);
        loadE(cb, 4*i+4, lane, e0);
        loadO(cb, 4*i+5, lane, o0);
        applyE(e1, xr, xi);
        applyO(o1, xr, xi, lane);
    }
}

// reverse: layers 63(O),62(E),...,1(O),0(E); same pipeline, rows descending.
static __device__ __forceinline__ void prop_rev(const float4* cb, int lane,
                                                float xr[4], float xi[4]) {
    CoefO o0, o1; CoefE e0, e1;
    loadO(cb, 63, lane, o0);
    loadE(cb, 62, lane, e0);
    for (int i = 0; i < 16; ++i) {
        loadO(cb, 61-4*i, lane, o1);      // i=15 -> rows -1/-2: in-bounds over-read
        loadE(cb, 60-4*i, lane, e1);      // (rev base >= row 64), values never used
        applyO(o0, xr, xi, lane);
        applyE(e0, xr, xi);
        loadO(cb, 59-4*i, lane, o0);
        loadE(cb, 58-4*i, lane, e0);
        applyO(o1, xr, xi, lane);
        applyE(e1, xr, xi);
    }
}

// 12 groups (it,chunk). chunk even: forward (S=Q^T); odd: reverse-transposed (S=Q);
// chunk 3 starts with gamma (S3=G*Q3). Chunks 1,2 are B-operands of the compose
// GEMMs: stored as CONJUGATE embedding [[Re,+Im],[-Im,Re]] so that in real
// arithmetic A*B^T = E(Sa)*E(conj Sb)^T = E(Sa*Sb^T)   [E(X)^T == E(X^H)].
__global__ void propagate_kernel(const float* __restrict__ coef,
                                 const float* __restrict__ coefT,
                                 const float* __restrict__ gexp,
                                 unsigned short* __restrict__ chunkH,
                                 unsigned short* __restrict__ chunkL)
{
    const int lane = threadIdx.x & 63;
    const int wv   = threadIdx.x >> 6;
    const int grp  = blockIdx.x >> 6;          // 0..11
    const int it   = grp >> 2, c = grp & 3;
    const int row  = (blockIdx.x & 63) * 4 + wv;
    const bool rev = (c & 1);
    const bool cj  = (c == 1) || (c == 2);     // conjugate-embedded storage

    float xr[4], xi[4];
    float gc = 1.0f, gs = 0.0f;
    if (c == 3) { gc = gexp[(it*NWG + row)*2]; gs = gexp[(it*NWG + row)*2 + 1]; }
#pragma unroll
    for (int e = 0; e < 4; ++e) {
        bool on = (4*lane + e) == row;
        xr[e] = on ? gc : 0.0f;
        xi[e] = on ? gs : 0.0f;
    }

    const float4* cb = (const float4*)(rev ? coefT : coef)
                     + ((size_t)(it*NWG + c*64) * NPAIR) * 2;

    if (!rev) prop_fwd(cb, lane, xr, xi);
    else      prop_rev(cb, lane, xr, xi);

    unsigned short* bh = chunkH + (size_t)grp * MSZ;
    unsigned short* bl = chunkL + (size_t)grp * MSZ;
    ushort4 reH, reL, imH, imL, nimH, nimL;
    unsigned short h, l;
#pragma unroll
    for (int e = 0; e < 4; ++e) {
        bsplit(xr[e], h, l);  ((unsigned short*)&reH)[e]  = h; ((unsigned short*)&reL)[e]  = l;
        bsplit(xi[e], h, l);  ((unsigned short*)&imH)[e]  = h; ((unsigned short*)&imL)[e]  = l;
        bsplit(-xi[e], h, l); ((unsigned short*)&nimH)[e] = h; ((unsigned short*)&nimL)[e] = l;
    }
    // plain:  [[Re, -Im],[ Im, Re]] ; conj: [[Re, +Im],[-Im, Re]]
    ushort4 urH = cj ? imH : nimH, urL = cj ? imL : nimL;   // upper-right
    ushort4 llH = cj ? nimH : imH, llL = cj ? nimL : imL;   // lower-left
    *(ushort4*)(bh + (size_t)row*KDIM + 4*lane)             = reH;
    *(ushort4*)(bh + (size_t)row*KDIM + 256 + 4*lane)       = urH;
    *(ushort4*)(bh + (size_t)(row+256)*KDIM + 4*lane)       = llH;
    *(ushort4*)(bh + (size_t)(row+256)*KDIM + 256 + 4*lane) = reH;
    *(ushort4*)(bl + (size_t)row*KDIM + 4*lane)             = reL;
    *(ushort4*)(bl + (size_t)row*KDIM + 256 + 4*lane)       = urL;
    *(ushort4*)(bl + (size_t)(row+256)*KDIM + 4*lane)       = llL;
    *(ushort4*)(bl + (size_t)(row+256)*KDIM + 256 + 4*lane) = reL;
}

// C = Ah*Bh^T + Ah*Bl^T + Al*Bh^T  (512x512, 64x64 tiles).
// mode0: z=it*2+wh. wh0: Pa^T = S0*S1^T (stored CONJUGATED: it is the B-operand
//        of mode1). wh1: Pb = S3*S2^T (stored plain). Outputs hi/lo split.
// mode1: z=it: E(M) = Pb * (Pa^T)^T -> bmat (single bf16)
__global__ __launch_bounds__(256, 2) void compose_kernel(
    const unsigned short* __restrict__ srcH, const unsigned short* __restrict__ srcL,
    unsigned short* __restrict__ outH, unsigned short* __restrict__ outL,
    unsigned short* __restrict__ bmat, int mode)
{
    __shared__ unsigned short sAh[2048], sAl[2048], sBh[2048], sBl[2048];
    const int z = blockIdx.z;
    const unsigned short *Ah, *Al, *Bh, *Bl;
    if (mode == 0) {
        int it = z >> 1, wh = z & 1;
        int ai = it*4 + (wh ? 3 : 0), bi = it*4 + (wh ? 2 : 1);
        Ah = srcH + (size_t)ai*MSZ; Al = srcL + (size_t)ai*MSZ;
        Bh = srcH + (size_t)bi*MSZ; Bl = srcL + (size_t)bi*MSZ;
    } else {
        Ah = srcH + (size_t)(2*z+1)*MSZ; Al = srcL + (size_t)(2*z+1)*MSZ;
        Bh = srcH + (size_t)(2*z)*MSZ;   Bl = srcL + (size_t)(2*z)*MSZ;
    }
    const int tid = threadIdx.x, lane = tid & 63, wv = tid >> 6;
    const int quad = lane >> 4, l16 = lane & 15;
    const int m0 = blockIdx.x * 64, n0 = blockIdx.y * 64;
    const unsigned short* src = (wv==0)?Ah:(wv==1)?Al:(wv==2)?Bh:Bl;
    unsigned short* dst = (wv==0)?sAh:(wv==1)?sAl:(wv==2)?sBh:sBl;
    const int r0 = (wv < 2) ? m0 : n0;
    const int trowb = lane >> 2, tcol = (lane & 3) * 8;

    floatx4 acc[4] = {};
    for (int kt = 0; kt < KDIM; kt += 32) {
        __syncthreads();
#pragma unroll
        for (int i = 0; i < 4; ++i)
            async16(src + (size_t)(r0 + i*16 + trowb)*KDIM + kt + tcol,
                    dst + i*512 + lane*8);
        __syncthreads();
        short8 ah = *(const short8*)&sAh[(16*wv + l16)*32 + quad*8];
        short8 al = *(const short8*)&sAl[(16*wv + l16)*32 + quad*8];
#pragma unroll
        for (int ni = 0; ni < 4; ++ni) {
            short8 bh = *(const short8*)&sBh[(16*ni + l16)*32 + quad*8];
            short8 bl = *(const short8*)&sBl[(16*ni + l16)*32 + quad*8];
            acc[ni] = __builtin_amdgcn_mfma_f32_16x16x32_bf16(ah, bh, acc[ni], 0,0,0);
            acc[ni] = __builtin_amdgcn_mfma_f32_16x16x32_bf16(ah, bl, acc[ni], 0,0,0);
            acc[ni] = __builtin_amdgcn_mfma_f32_16x16x32_bf16(al, bh, acc[ni], 0,0,0);
        }
    }
#pragma unroll
    for (int ni = 0; ni < 4; ++ni)
#pragma unroll
        for (int rg = 0; rg < 4; ++rg) {
            int r = m0 + 16*wv + quad*4 + rg;
            int cc = n0 + 16*ni + l16;
            float v = acc[ni][rg];
            if (mode == 0) {
                // wh==0 (z even): store conjugate embedding -> negate Im quadrants
                float vs = (((z & 1) == 0) && ((r >= 256) != (cc >= 256))) ? -v : v;
                unsigned short h, l; bsplit(vs, h, l);
                outH[(size_t)z*MSZ + (size_t)r*KDIM + cc] = h;
                outL[(size_t)z*MSZ + (size_t)r*KDIM + cc] = l;
            } else {
                bmat[(size_t)z*MSZ + (size_t)r*KDIM + cc] = f2bf(v);
            }
        }
}

__global__ void convert_kernel(const float* __restrict__ xre,
                               const float* __restrict__ xim,
                               unsigned short* __restrict__ xb)
{
    int idx = blockIdx.x * 256 + threadIdx.x;
    int b = idx >> 8, j = idx & 255;
    xb[(size_t)b * KDIM + j]       = f2bf(xre[idx]);
    xb[(size_t)b * KDIM + 256 + j] = f2bf(xim[idx]);
}

// out[b][n] = sum_k x[b][k]*Bm[n][k]. 64x128 tile; tile rows of Bm: {n0..n0+63}
// real rows, {n0+256..n0+319} imag rows -> in-register (re,im) pairing.
// mode 0/1: EO nonlin -> bf16 xout ; mode 2: intensity -> fp32 Iout.
__global__ __launch_bounds__(256, 2) void gemm_kernel(
    const unsigned short* __restrict__ A, const unsigned short* __restrict__ Bm,
    int mode, unsigned short* __restrict__ xout, float* __restrict__ Iout)
{
    __shared__ unsigned short sA[64*32];
    __shared__ unsigned short sB[128*32];
    const int tid = threadIdx.x, lane = tid & 63, wv = tid >> 6;
    const int quad = lane >> 4, l16 = lane & 15;
    const int m0 = blockIdx.x * 64, n0 = blockIdx.y * 64;
    const int trowb = lane >> 2, tcol = (lane & 3) * 8;

    floatx4 acc[8] = {};
    for (int kt = 0; kt < KDIM; kt += 32) {
        __syncthreads();
        async16(A + (size_t)(m0 + 16*wv + trowb)*KDIM + kt + tcol,
                &sA[wv*512 + lane*8]);
#pragma unroll
        for (int j = 0; j < 2; ++j) {
            int trow = 32*wv + 16*j + trowb;
            int grow = (trow < 64) ? (n0 + trow) : (n0 + trow + 192);
            async16(Bm + (size_t)grow*KDIM + kt + tcol,
                    &sB[(32*wv + 16*j)*32 + lane*8]);
        }
        __syncthreads();
        short8 a = *(const short8*)&sA[(16*wv + l16)*32 + quad*8];
#pragma unroll
        for (int ni = 0; ni < 8; ++ni) {
            short8 b = *(const short8*)&sB[(16*ni + l16)*32 + quad*8];
            acc[ni] = __builtin_amdgcn_mfma_f32_16x16x32_bf16(a, b, acc[ni], 0,0,0);
        }
    }
#pragma unroll
    for (int ni = 0; ni < 4; ++ni)
#pragma unroll
        for (int rg = 0; rg < 4; ++rg) {
            int row = m0 + 16*wv + quad*4 + rg;
            int cc  = n0 + 16*ni + l16;
            float yr = acc[ni][rg], yi = acc[ni+4][rg];
            if (mode == 2) {
                Iout[(size_t)row*256 + cc] = yr*yr + yi*yi;
            } else {
                float I = yr*yr + yi*yi;
                float phase = 0.078539816339744831f * I + 1.5707963267948966f;
                float sp, cp; __sincosf(phase, &sp, &cp);
                float f = 0.94868329805051381f * cp;
                xout[(size_t)row*KDIM + cc]       = f2bf(f*(cp*yr + sp*yi));
                xout[(size_t)row*KDIM + cc + 256] = f2bf(f*(cp*yi - sp*yr));
            }
        }
}

__global__ void final_kernel(const float* __restrict__ Ibuf,
                             float* __restrict__ out)
{
    const int lane = threadIdx.x & 63;
    const int wv   = threadIdx.x >> 6;
    const int row  = blockIdx.x * 4 + wv;
    float4 v = *(const float4*)(Ibuf + (size_t)row * 256 + 4*lane);
    float ss = v.x*v.x + v.y*v.y + v.z*v.z + v.w*v.w;
#pragma unroll
    for (int d = 1; d < 64; d <<= 1) ss += __shfl_xor(ss, d, 64);
    float inv = 1.0f / fmaxf(sqrtf(ss), 1e-12f);
    float* o = out + (size_t)row * 10;
    if (lane == 0)      { o[0]=v.x*inv; o[1]=v.y*inv; o[2]=v.z*inv; o[3]=v.w*inv; }
    else if (lane == 1) { o[4]=v.x*inv; o[5]=v.y*inv; o[6]=v.z*inv; o[7]=v.w*inv; }
    else if (lane == 2) { o[8]=v.x*inv; o[9]=v.y*inv; }
}

extern "C" void kernel_launch(void* const* d_in, const int* in_sizes, int n_in,
                              void* d_out, int out_size, void* d_ws, size_t ws_size,
                              hipStream_t stream)
{
    const float* x_real = (const float*)d_in[0];
    const float* x_imag = (const float*)d_in[1];
    const float* theta  = (const float*)d_in[2];
    const float* phi    = (const float*)d_in[3];
    const float* gamma  = (const float*)d_in[4];

    char* ws = (char*)d_ws;
    float* coef  = (float*)(ws + 0);              // 3 MB   [precompute->propagate]
    float* coefT = (float*)(ws + 3145728);        // 3 MB
    float* gexp  = (float*)(ws + 6291456);        // 6 KB
    unsigned short* chunkH = (unsigned short*)(ws + 6297600);   // 6 MB
    unsigned short* chunkL = (unsigned short*)(ws + 12589056);  // 6 MB
    unsigned short* PH   = (unsigned short*)(ws + 0);           // 3 MB (alias coef)
    unsigned short* PL   = (unsigned short*)(ws + 3145728);     // 3 MB (alias coefT)
    unsigned short* xbuf0 = (unsigned short*)(ws + 6297600);    // 8 MB (alias chunks)
    unsigned short* xbuf1 = (unsigned short*)(ws + 14686208);   // 8 MB
    float* Ibuf = (float*)(ws + 14686208);                      // 8 MB (alias xbuf1)
    unsigned short* Bmat = (unsigned short*)(ws + 23074816);    // 1.5 MB

    precompute_kernel<<<(NITER*NWG*NPAIR + 255)/256, 256, 0, stream>>>(
        theta, phi, gamma, coef, coefT, gexp);

    propagate_kernel<<<768, 256, 0, stream>>>(coef, coefT, gexp, chunkH, chunkL);

    compose_kernel<<<dim3(8,8,6), 256, 0, stream>>>(chunkH, chunkL, PH, PL, Bmat, 0);
    compose_kernel<<<dim3(8,8,3), 256, 0, stream>>>(PH, PL, PH, PL, Bmat, 1);

    convert_kernel<<<NBATCH*NWG/256, 256, 0, stream>>>(x_real, x_imag, xbuf0);

    gemm_kernel<<<dim3(128,4), 256, 0, stream>>>(xbuf0, Bmat,           0, xbuf1, (float*)nullptr);
    gemm_kernel<<<dim3(128,4), 256, 0, stream>>>(xbuf1, Bmat + MSZ,     1, xbuf0, (float*)nullptr);
    gemm_kernel<<<dim3(128,4), 256, 0, stream>>>(xbuf0, Bmat + 2*MSZ,   2, (unsigned short*)nullptr, Ibuf);

    final_kernel<<<NBATCH/4, 256, 0, stream>>>(Ibuf, (float*)d_out);
}